// Round 8
// baseline (192.367 us; speedup 1.0000x reference)
//
#include <hip/hip_runtime.h>
#include <math.h>

#define P_N 64
#define B_N 32
#define A_N 40
#define D_N 128

// ---- helpers: uniform-lane broadcast (VALU latency, not ds_bpermute) ----
__device__ __forceinline__ int readlane_i(int v, int l) {
  return __builtin_amdgcn_readlane(v, l);
}
__device__ __forceinline__ float readlane_f(float v, int l) {
  return __int_as_float(__builtin_amdgcn_readlane(__float_as_int(v), l));
}
// order-preserving float->uint map, branch-free (2 dependent VALU)
__device__ __forceinline__ unsigned ordf(float f) {
  unsigned b = __float_as_uint(f);
  return b ^ (((unsigned)((int)b >> 31)) | 0x80000000u);
}
// full-wave min via DPP (gfx9 canonical sequence), result broadcast from lane 63
__device__ __forceinline__ unsigned wave_min_u32(unsigned x) {
  unsigned t;
  t = (unsigned)__builtin_amdgcn_update_dpp((int)0xFFFFFFFFu, (int)x, 0x111, 0xF, 0xF, false); // row_shr:1
  x = t < x ? t : x;
  t = (unsigned)__builtin_amdgcn_update_dpp((int)0xFFFFFFFFu, (int)x, 0x112, 0xF, 0xF, false); // row_shr:2
  x = t < x ? t : x;
  t = (unsigned)__builtin_amdgcn_update_dpp((int)0xFFFFFFFFu, (int)x, 0x114, 0xF, 0xF, false); // row_shr:4
  x = t < x ? t : x;
  t = (unsigned)__builtin_amdgcn_update_dpp((int)0xFFFFFFFFu, (int)x, 0x118, 0xF, 0xF, false); // row_shr:8
  x = t < x ? t : x;
  t = (unsigned)__builtin_amdgcn_update_dpp((int)0xFFFFFFFFu, (int)x, 0x142, 0xA, 0xF, false); // row_bcast:15
  x = t < x ? t : x;
  t = (unsigned)__builtin_amdgcn_update_dpp((int)0xFFFFFFFFu, (int)x, 0x143, 0xC, 0xF, false); // row_bcast:31
  x = t < x ? t : x;
  return (unsigned)__builtin_amdgcn_readlane((int)x, 63);
}

// ---- constant-index register mux (rule #20: never dynamic-index a local array) ----
__device__ __forceinline__ float mux8(float r0, float r1, float r2, float r3,
                                      float r4, float r5, float r6, float r7, int k) {
  float a = (k & 1) ? r1 : r0;
  float b = (k & 1) ? r3 : r2;
  float c = (k & 1) ? r5 : r4;
  float d = (k & 1) ? r7 : r6;
  float e = (k & 2) ? b : a;
  float f = (k & 2) ? d : c;
  return (k & 4) ? f : e;
}
// wave-uniform index k in [0,40): scalar branch on group, cndmask mux within
__device__ __forceinline__ float sel40_u(const float (&R)[A_N], int k) {
  int kk = k & 7;
  switch (k >> 3) {
    case 0:  return mux8(R[0],  R[1],  R[2],  R[3],  R[4],  R[5],  R[6],  R[7],  kk);
    case 1:  return mux8(R[8],  R[9],  R[10], R[11], R[12], R[13], R[14], R[15], kk);
    case 2:  return mux8(R[16], R[17], R[18], R[19], R[20], R[21], R[22], R[23], kk);
    case 3:  return mux8(R[24], R[25], R[26], R[27], R[28], R[29], R[30], R[31], kk);
    default: return mux8(R[32], R[33], R[34], R[35], R[36], R[37], R[38], R[39], kk);
  }
}
// divergent index k in [0,40): full cndmask tree
__device__ __forceinline__ float sel40_v(const float (&R)[A_N], int k) {
  int kk = k & 7, g = k >> 3;
  float m0 = mux8(R[0],  R[1],  R[2],  R[3],  R[4],  R[5],  R[6],  R[7],  kk);
  float m1 = mux8(R[8],  R[9],  R[10], R[11], R[12], R[13], R[14], R[15], kk);
  float m2 = mux8(R[16], R[17], R[18], R[19], R[20], R[21], R[22], R[23], kk);
  float m3 = mux8(R[24], R[25], R[26], R[27], R[28], R[29], R[30], R[31], kk);
  float m4 = mux8(R[32], R[33], R[34], R[35], R[36], R[37], R[38], R[39], kk);
  float t01 = (g & 1) ? m1 : m0;
  float t23 = (g & 1) ? m3 : m2;
  float t   = (g & 2) ? t23 : t01;
  return (g & 4) ? m4 : t;
}

// ---------------- Hungarian (JV) — one wave per (p,b) cost matrix ----------------
// Lane j = column j (0 = dummy, 1..40 real); lane j BUILDS AND HOLDS column j-1
// of C entirely in registers (Creg[40]) — no LDS cost matrix, no ds_read on the
// Dijkstra critical chain (register mux instead). Lane r also holds u[r].
// Init = column reduction + col-greedy + row-pass greedy (tight u only on rows
// actually assigned). Search = deferred-potential Dijkstra; key packs
// (val20|p6|lane6); exclusion folded into off as excl=+INF.
__global__ __launch_bounds__(64, 2) void hungarian_pair(
    const float* __restrict__ DP, const float* __restrict__ X,
    const float* __restrict__ G, float* __restrict__ out) {
  __shared__ float g_lds[D_N];
  const int bid  = blockIdx.x;
  const int lane = threadIdx.x;
  const bool realcol = (lane >= 1 && lane <= A_N);
  const int  cix     = realcol ? (lane - 1) : 0;
  const float* __restrict__ Abase = DP + (bid >> 5) * (A_N * D_N);
  const float* __restrict__ Bbase = X  + (bid & 31) * (A_N * D_N);

  // exp(gamma) once (2 expf/lane instead of 128)
  g_lds[lane]      = expf(G[lane]);
  g_lds[lane + 64] = expf(G[lane + 64]);
  __syncthreads();

  // ---- build C[i][lane-1] = |g*(A_i - B_{lane-1})|^2 into registers ----
  float Creg[A_N];
  #pragma unroll
  for (int i = 0; i < A_N; ++i) Creg[i] = 0.f;
  if (realcol) {
    const float* bp = Bbase + cix * D_N;
    for (int c = 0; c < 4; ++c) {                   // 4 chunks of 32 dims
      float4 gg[8], bb[8];
      #pragma unroll
      for (int k = 0; k < 8; ++k) {
        gg[k] = ((const float4*)(g_lds + c * 32))[k];        // uniform LDS broadcast
        float4 br = ((const float4*)(bp + c * 32))[k];
        bb[k] = make_float4(br.x * gg[k].x, br.y * gg[k].y,
                            br.z * gg[k].z, br.w * gg[k].w);
      }
      #pragma unroll
      for (int i = 0; i < A_N; ++i) {
        const float4* ap = (const float4*)(Abase + i * D_N + c * 32); // uniform -> scalar
        float s = 0.f;
        #pragma unroll
        for (int k = 0; k < 8; ++k) {
          float4 a = ap[k];
          float dx = fmaf(a.x, gg[k].x, -bb[k].x); s = fmaf(dx, dx, s);
          float dy = fmaf(a.y, gg[k].y, -bb[k].y); s = fmaf(dy, dy, s);
          float dz = fmaf(a.z, gg[k].z, -bb[k].z); s = fmaf(dz, dz, s);
          float dw = fmaf(a.w, gg[k].w, -bb[k].w); s = fmaf(dw, dw, s);
        }
        Creg[i] += s;
      }
    }
  }

  // ---- column reduction: v[j] = min_i C[i][j], remember argmin row ----
  float vpot = 0.f;
  int   amin = 0;                        // 1-based argmin row for this column
  if (realcol) {
    float mn = Creg[0]; int mi = 0;
    #pragma unroll
    for (int i = 1; i < A_N; ++i) {
      if (Creg[i] < mn) { mn = Creg[i]; mi = i; }
    }
    vpot = mn; amin = mi + 1;
  }

  // ---- greedy pass 1: column argmins on tight edges (u=0, v=colmin) ----
  unsigned long long rmask = 0ull;       // bit r = row r matched (uniform across lanes)
  int p = 0, way = 0;                    // p: row matched to this column (0 = free)
  for (int j = 1; j <= A_N; ++j) {
    int am = readlane_i(amin, j);
    if (!((rmask >> am) & 1ull)) {
      rmask |= 1ull << am;
      if (lane == j) p = am;
    }
  }

  float u = 0.f;                         // row potential (lane = row 1..40)

  // ---- greedy pass 2 (row pass): assign free rows on free argmin cols only ----
  for (int i = 1; i <= A_N; ++i) {
    if ((rmask >> i) & 1ull) continue;
    float r = realcol ? (sel40_u(Creg, i - 1) - vpot) : INFINITY;
    unsigned key = (ordf(r) & 0xFFFFFFC0u) | (unsigned)lane;
    unsigned kmin = wave_min_u32(key);
    int jm = (int)(kmin & 63u);
    int pj = readlane_i(p, jm);
    if (pj == 0) {                        // argmin column free -> assign tight edge
      float rmin = readlane_f(r, jm);
      if (lane == jm) p = i;
      if (lane == i)  u = rmin;
      rmask |= 1ull << i;
    }
  }

  // ---- shortest augmenting path for remaining free rows (deferred potentials) ----
  for (int f = 1; f <= A_N; ++f) {
    if ((rmask >> f) & 1ull) continue;   // matched — skip (wave-uniform)
    if (lane == 0) p = f;                // p[0] = f  (augmentation reads this!)
    float mhat = INFINITY;               // min_i (A_j(i) + Dsum_entry(i))
    float excl = realcol ? 0.f : INFINITY; // +INF once this column leaves the frontier
    float dsum = 0.f;                    // accumulated delta (current Dijkstra radius)
    float dent = 0.f, rent = 0.f;        // Dsum when this col became used / row entered
    bool  used   = !realcol;
    bool  intree = (lane == f);
    int   j0 = 0, i0 = f;
    const unsigned plane_key = ((unsigned)p << 6) | (unsigned)lane; // p static in-search
    for (int guard = 0; guard < 42; ++guard) {
      float Craw = sel40_u(Creg, i0 - 1);           // register mux — no LDS on chain
      float uc   = readlane_f(u, i0);
      float off  = dsum - uc - vpot + excl;         // INF if excluded
      float cand = Craw + off;
      if (cand < mhat) way = j0;                    // off-chain cndmask
      mhat = fminf(mhat, cand);
      unsigned key = (ordf(mhat) & 0xFFFFF000u) | plane_key;
      unsigned kmin = wave_min_u32(key);
      int j1 = (int)(kmin & 63u);
      int i1 = (int)((kmin >> 6) & 63u);            // p[j1] from the key — no readlane
      float dnew = readlane_f(mhat, j1);            // exact popped distance
      if (lane == j1) { used = true; dent = dnew; excl = INFINITY; mhat = INFINITY; }
      dsum = dnew;
      j0 = j1;
      i0 = i1;
      if (i1 == 0) break;                           // free column reached
      if (lane == i1) { intree = true; rent = dnew; }
    }
    // batched potential updates: v[j] -= (Dfinal - Dent_j), u[i] += (Dfinal - Rent_i)
    if (used && realcol) vpot -= (dsum - dent);
    if (intree)          u    += (dsum - rent);
    // augment along way[] back to the dummy column
    while (j0 != 0) {
      int jn = readlane_i(way, j0);
      int pn = readlane_i(p, jn);
      if (lane == j0) p = pn;
      j0 = jn;
    }
  }

  // ---- matched-kernel value: sum_j exp(-C[p[j]-1][j-1]) / 40 ----
  int   pk = realcol ? (p - 1) : 0;      // divergent index
  float cm = sel40_v(Creg, pk);
  float e  = realcol ? expf(-cm) : 0.f;
  #pragma unroll
  for (int off = 32; off; off >>= 1) e += __shfl_xor(e, off);
  if (lane == 0) out[bid] = e / 40.0f;
}

// ---------------- mean + triangular solve + var (kxx == 1.0, see note) ----------------
// Self-distance diagonal is |v-v|^2 = 0 (ref: abs(-2*dot+s+s) ~ 1e-6), Hungarian on it
// is identity, so kxx = sum(exp(-~0))/40 = 1 - O(1e-6). Hard-code 1.0f.
__global__ __launch_bounds__(64) void final_kernel(
    const float* __restrict__ Kx, const float* __restrict__ L,
    const float* __restrict__ alpha, float* __restrict__ out) {
  __shared__ float vl[P_N * B_N];
  int b = threadIdx.x;
  if (b >= B_N) return;
  float mean = 0.f;
  for (int p = 0; p < P_N; ++p) mean = fmaf(Kx[p * B_N + b], alpha[p], mean);
  out[b] = mean;
  // forward substitution: L * v = Kx[:, b]   (== inv(L) @ Kx)
  float sumv2 = 0.f;
  for (int i = 0; i < P_N; ++i) {
    float s = Kx[i * B_N + b];
    for (int j = 0; j < i; ++j) s = fmaf(-L[i * P_N + j], vl[j * B_N + b], s);
    float vi = s / L[i * P_N + i];
    vl[i * B_N + b] = vi;
    sumv2 = fmaf(vi, vi, sumv2);
  }
  out[B_N + b] = 1.0f - sumv2;
}

extern "C" void kernel_launch(void* const* d_in, const int* in_sizes, int n_in,
                              void* d_out, int out_size, void* d_ws, size_t ws_size,
                              hipStream_t stream) {
  const float* x     = (const float*)d_in[0];   // [32,40,128]
  const float* dp    = (const float*)d_in[1];   // [64,40,128]
  const float* gamma = (const float*)d_in[2];   // [1,128]
  const float* L     = (const float*)d_in[3];   // [64,64]
  const float* alpha = (const float*)d_in[4];   // [64]
  float* out = (float*)d_out;                   // mean[32] ++ var[32]

  float* Kx = (float*)d_ws;                     // 2048 f32

  hungarian_pair<<<P_N * B_N, 64, 0, stream>>>(dp, x, gamma, Kx);
  final_kernel<<<1, 64, 0, stream>>>(Kx, L, alpha, out);
}

// Round 9
// 129.478 us; speedup vs baseline: 1.4857x; 1.4857x over previous
//
#include <hip/hip_runtime.h>
#include <math.h>

#define P_N 64
#define B_N 32
#define A_N 40
#define D_N 128

// ---- helpers: uniform-lane broadcast (VALU latency, not ds_bpermute) ----
__device__ __forceinline__ int readlane_i(int v, int l) {
  return __builtin_amdgcn_readlane(v, l);
}
__device__ __forceinline__ float readlane_f(float v, int l) {
  return __int_as_float(__builtin_amdgcn_readlane(__float_as_int(v), l));
}
// order-preserving float->uint map, branch-free (2 dependent VALU)
__device__ __forceinline__ unsigned ordf(float f) {
  unsigned b = __float_as_uint(f);
  return b ^ (((unsigned)((int)b >> 31)) | 0x80000000u);
}
// full-wave min via DPP (gfx9 canonical sequence), result broadcast from lane 63
__device__ __forceinline__ unsigned wave_min_u32(unsigned x) {
  unsigned t;
  t = (unsigned)__builtin_amdgcn_update_dpp((int)0xFFFFFFFFu, (int)x, 0x111, 0xF, 0xF, false); // row_shr:1
  x = t < x ? t : x;
  t = (unsigned)__builtin_amdgcn_update_dpp((int)0xFFFFFFFFu, (int)x, 0x112, 0xF, 0xF, false); // row_shr:2
  x = t < x ? t : x;
  t = (unsigned)__builtin_amdgcn_update_dpp((int)0xFFFFFFFFu, (int)x, 0x114, 0xF, 0xF, false); // row_shr:4
  x = t < x ? t : x;
  t = (unsigned)__builtin_amdgcn_update_dpp((int)0xFFFFFFFFu, (int)x, 0x118, 0xF, 0xF, false); // row_shr:8
  x = t < x ? t : x;
  t = (unsigned)__builtin_amdgcn_update_dpp((int)0xFFFFFFFFu, (int)x, 0x142, 0xA, 0xF, false); // row_bcast:15
  x = t < x ? t : x;
  t = (unsigned)__builtin_amdgcn_update_dpp((int)0xFFFFFFFFu, (int)x, 0x143, 0xC, 0xF, false); // row_bcast:31
  x = t < x ? t : x;
  return (unsigned)__builtin_amdgcn_readlane((int)x, 63);
}

// ---------------- Hungarian (JV) — one wave per (p,b) cost matrix ----------------
// R7 structure (verified 124 µs steady-state): LDS cost matrix (R8's all-register
// C silently went to scratch — VGPR_Count stayed 84 — and regressed 60%).
// Lane j = column j (0 = dummy, 1..40 real). Lane r also holds row-potential u[r].
// Build fuses gamma scaling; exp(gamma) staged once in LDS. Init = column
// reduction + col-greedy + row-pass greedy (tight u only on assigned rows).
// Search = deferred-potential Dijkstra; key packs (val20|p6|lane6); exclusion
// folded into the load-shadow offset as excl=+INF.
__global__ __launch_bounds__(64) void hungarian_pair(
    const float* __restrict__ DP, const float* __restrict__ X,
    const float* __restrict__ G, float* __restrict__ out) {
  __shared__ float Cs[A_N * A_N];
  __shared__ float g_lds[D_N];
  const int bid  = blockIdx.x;
  const int lane = threadIdx.x;
  const float* __restrict__ Abase = DP + (bid >> 5) * (A_N * D_N);
  const float* __restrict__ Bbase = X  + (bid & 31) * (A_N * D_N);

  // exp(gamma) once (2 expf/lane instead of 128)
  g_lds[lane]      = expf(G[lane]);
  g_lds[lane + 64] = expf(G[lane + 64]);
  __syncthreads();

  // ---- build C[i][j] = |g*(A_i - B_j)|^2 ; lane j owns column j ----
  if (lane < A_N) {
    const float* bp = Bbase + lane * D_N;
    for (int c = 0; c < 4; ++c) {                   // 4 chunks of 32 dims
      float4 gg[8], bb[8];
      #pragma unroll
      for (int k = 0; k < 8; ++k) {
        gg[k] = ((const float4*)(g_lds + c * 32))[k];        // uniform LDS -> broadcast
        float4 br = ((const float4*)(bp + c * 32))[k];
        bb[k] = make_float4(br.x * gg[k].x, br.y * gg[k].y,
                            br.z * gg[k].z, br.w * gg[k].w);
      }
      for (int i = 0; i < A_N; ++i) {
        const float4* ap = (const float4*)(Abase + i * D_N + c * 32); // uniform -> broadcast
        float s = 0.f;
        #pragma unroll
        for (int k = 0; k < 8; ++k) {
          float4 a = ap[k];
          float dx = fmaf(a.x, gg[k].x, -bb[k].x); s = fmaf(dx, dx, s);
          float dy = fmaf(a.y, gg[k].y, -bb[k].y); s = fmaf(dy, dy, s);
          float dz = fmaf(a.z, gg[k].z, -bb[k].z); s = fmaf(dz, dz, s);
          float dw = fmaf(a.w, gg[k].w, -bb[k].w); s = fmaf(dw, dw, s);
        }
        if (c == 0) Cs[i * A_N + lane] = s;
        else        Cs[i * A_N + lane] += s;
      }
    }
  }
  __syncthreads();

  const int  cix     = (lane >= 1 && lane <= A_N) ? (lane - 1) : 0;
  const bool realcol = (lane >= 1 && lane <= A_N);

  // ---- column reduction: v[j] = min_i C[i][j], remember argmin row ----
  float vpot = 0.f;
  int   amin = 0;                        // 1-based argmin row for this column
  if (realcol) {
    float mn = INFINITY; int mi = 0;
    for (int i = 0; i < A_N; ++i) {
      float c = Cs[i * A_N + cix];
      if (c < mn) { mn = c; mi = i; }
    }
    vpot = mn; amin = mi + 1;
  }

  // ---- greedy pass 1: column argmins on tight edges (u=0, v=colmin) ----
  unsigned long long rmask = 0ull;       // bit r = row r matched (uniform across lanes)
  int p = 0, way = 0;                    // p: row matched to this column (0 = free)
  for (int j = 1; j <= A_N; ++j) {
    int am = readlane_i(amin, j);
    if (!((rmask >> am) & 1ull)) {
      rmask |= 1ull << am;
      if (lane == j) p = am;
    }
  }

  float u = 0.f;                         // row potential (lane = row 1..40)

  // ---- greedy pass 2 (row pass): for each free row, rowmin over (C - v);
  //      assign iff argmin col free, setting u[i]=rowmin (tight). Unassigned
  //      rows keep u=0 (loose, admissible) — avoids R4's cascade regression.
  for (int i = 1; i <= A_N; ++i) {
    if ((rmask >> i) & 1ull) continue;
    float r = realcol ? (Cs[(i - 1) * A_N + cix] - vpot) : INFINITY;
    unsigned key = (ordf(r) & 0xFFFFFFC0u) | (unsigned)lane;
    unsigned kmin = wave_min_u32(key);
    int jm = (int)(kmin & 63u);
    int pj = readlane_i(p, jm);
    if (pj == 0) {                        // argmin column free -> assign tight edge
      float rmin = readlane_f(r, jm);
      if (lane == jm) p = i;
      if (lane == i)  u = rmin;
      rmask |= 1ull << i;
    }
  }

  // ---- shortest augmenting path for remaining free rows (deferred potentials) ----
  for (int f = 1; f <= A_N; ++f) {
    if ((rmask >> f) & 1ull) continue;   // matched — skip (wave-uniform)
    if (lane == 0) p = f;                // p[0] = f  (augmentation reads this!)
    float mhat = INFINITY;               // min_i (A_j(i) + Dsum_entry(i))
    float excl = realcol ? 0.f : INFINITY; // +INF once this column leaves the frontier
    float dsum = 0.f;                    // accumulated delta (current Dijkstra radius)
    float dent = 0.f, rent = 0.f;        // Dsum when this col became used / row entered
    bool  used   = !realcol;
    bool  intree = (lane == f);
    int   j0 = 0, i0 = f;
    const unsigned plane_key = ((unsigned)p << 6) | (unsigned)lane; // p static in-search
    for (int guard = 0; guard < 42; ++guard) {
      float Craw = Cs[(i0 - 1) * A_N + cix];        // ds_read issues first
      float uc   = readlane_f(u, i0);               // overlaps LDS latency
      float off  = dsum - uc - vpot + excl;         // load-shadow; INF if excluded
      float cand = Craw + off;                      // 1 VALU after load
      if (cand < mhat) way = j0;                    // off-chain cndmask
      mhat = fminf(mhat, cand);
      unsigned key = (ordf(mhat) & 0xFFFFF000u) | plane_key;
      unsigned kmin = wave_min_u32(key);
      int j1 = (int)(kmin & 63u);
      int i1 = (int)((kmin >> 6) & 63u);            // p[j1] from the key — no readlane
      float dnew = readlane_f(mhat, j1);            // exact popped distance
      if (lane == j1) { used = true; dent = dnew; excl = INFINITY; mhat = INFINITY; }
      dsum = dnew;
      j0 = j1;
      i0 = i1;
      if (i1 == 0) break;                           // free column reached
      if (lane == i1) { intree = true; rent = dnew; }
    }
    // batched potential updates: v[j] -= (Dfinal - Dent_j), u[i] += (Dfinal - Rent_i)
    if (used && realcol) vpot -= (dsum - dent);
    if (intree)          u    += (dsum - rent);
    // augment along way[] back to the dummy column
    while (j0 != 0) {
      int jn = readlane_i(way, j0);
      int pn = readlane_i(p, jn);
      if (lane == j0) p = pn;
      j0 = jn;
    }
  }

  // ---- matched-kernel value: sum_j exp(-C[p[j]-1][j-1]) / 40 ----
  float e = 0.f;
  if (realcol) e = expf(-Cs[(p - 1) * A_N + (lane - 1)]);
  #pragma unroll
  for (int off = 32; off; off >>= 1) e += __shfl_xor(e, off);
  if (lane == 0) out[bid] = e / 40.0f;
}

// ---------------- mean + triangular solve + var (kxx == 1.0, see note) ----------------
// Self-distance diagonal is |v-v|^2 = 0 (ref: abs(-2*dot+s+s) ~ 1e-6), Hungarian on it
// is identity, so kxx = sum(exp(-~0))/40 = 1 - O(1e-6). Hard-code 1.0f.
// Forward substitution fully unrolled: each thread's 64 solve values live in
// registers with static indices (was: LDS round-trip inside the serial inner
// loop -> ~20 µs latency-bound; now ~2000 pipelined fmaf).
__global__ __launch_bounds__(64) void final_kernel(
    const float* __restrict__ Kx, const float* __restrict__ L,
    const float* __restrict__ alpha, float* __restrict__ out) {
  int b = threadIdx.x;
  if (b >= B_N) return;
  float mean = 0.f;
  #pragma unroll
  for (int p = 0; p < P_N; ++p) mean = fmaf(Kx[p * B_N + b], alpha[p], mean);
  out[b] = mean;
  // forward substitution: L * v = Kx[:, b]   (== inv(L) @ Kx), v in registers
  float vr[P_N];
  float sumv2 = 0.f;
  #pragma unroll
  for (int i = 0; i < P_N; ++i) {
    float s = Kx[i * B_N + b];
    #pragma unroll
    for (int j = 0; j < i; ++j) s = fmaf(-L[i * P_N + j], vr[j], s);
    float vi = s / L[i * P_N + i];
    vr[i] = vi;
    sumv2 = fmaf(vi, vi, sumv2);
  }
  out[B_N + b] = 1.0f - sumv2;
}

extern "C" void kernel_launch(void* const* d_in, const int* in_sizes, int n_in,
                              void* d_out, int out_size, void* d_ws, size_t ws_size,
                              hipStream_t stream) {
  const float* x     = (const float*)d_in[0];   // [32,40,128]
  const float* dp    = (const float*)d_in[1];   // [64,40,128]
  const float* gamma = (const float*)d_in[2];   // [1,128]
  const float* L     = (const float*)d_in[3];   // [64,64]
  const float* alpha = (const float*)d_in[4];   // [64]
  float* out = (float*)d_out;                   // mean[32] ++ var[32]

  float* Kx = (float*)d_ws;                     // 2048 f32

  hungarian_pair<<<P_N * B_N, 64, 0, stream>>>(dp, x, gamma, Kx);
  final_kernel<<<1, 64, 0, stream>>>(Kx, L, alpha, out);
}